// Round 1
// baseline (1208.429 us; speedup 1.0000x reference)
//
#include <hip/hip_runtime.h>
#include <math.h>

// Problem constants
constexpr int kB  = 2048;
constexpr int kNG = 20000;
constexpr int kP  = 256;
constexpr int kG  = 64;
constexpr int kE  = 128;
constexpr int kT  = 32;
// H=4, HD=32
constexpr int kNPG = 16;   // number of pathway groups
constexpr int kPPG = 16;   // pathways per group
constexpr int kBT  = 64;   // batch tile
constexpr int kNBT = kB / kBT; // 32

// ---------------------------------------------------------------------------
// K1: token GEMM pass A — accumulate sum over p of relu(xg@Wp + bp) into meanSum
// grid (kNBT, kNPG), 256 threads
// ---------------------------------------------------------------------------
__global__ __launch_bounds__(256) void k_meanpass(
    const float* __restrict__ xg, const int* __restrict__ pidx,
    const float* __restrict__ Wp, const float* __restrict__ bp,
    float* __restrict__ meanSum)
{
    __shared__ __align__(16) float wp[kG][kE];   // 32 KB
    __shared__ __align__(16) float xs[kBT][kG];  // 16 KB
    __shared__ float bps[kE];

    const int tid = threadIdx.x;
    const int b0  = blockIdx.x * kBT;
    const int pg  = blockIdx.y;
    const int eq  = tid & 31;        // e-quad index
    const int e0  = eq * 4;
    const int bq8 = (tid >> 5) * 8;  // base batch row of this thread's 8 rows

    float macc[8][4];
#pragma unroll
    for (int i = 0; i < 8; ++i)
#pragma unroll
        for (int j = 0; j < 4; ++j) macc[i][j] = 0.f;

    const int gfix = tid & 63;
    const int bb   = tid >> 6;

    for (int pp = 0; pp < kPPG; ++pp) {
        const int p = pg * kPPG + pp;
        // stage Wp[p] (2048 float4)
        const float4* wsrc = (const float4*)(Wp + (size_t)p * kG * kE);
        float4* wdst = (float4*)(&wp[0][0]);
#pragma unroll
        for (int it = 0; it < 8; ++it) wdst[it * 256 + tid] = wsrc[it * 256 + tid];
        if (tid < kE) bps[tid] = bp[p * kE + tid];
        // stage gathered x tile: thread owns column gfix
        {
            const int c = pidx[p * kG + gfix];
#pragma unroll
            for (int it = 0; it < 16; ++it) {
                const int bi = bb * 16 + it;
                xs[bi][gfix] = xg[(size_t)(b0 + bi) * kNG + c];
            }
        }
        __syncthreads();

        float bpr[4];
#pragma unroll
        for (int j = 0; j < 4; ++j) bpr[j] = bps[e0 + j];

        float acc[8][4];
#pragma unroll
        for (int i = 0; i < 8; ++i)
#pragma unroll
            for (int j = 0; j < 4; ++j) acc[i][j] = 0.f;

#pragma unroll 4
        for (int gq = 0; gq < 16; ++gq) {
            const int g0 = gq * 4;
            float4 wrow[4];
#pragma unroll
            for (int k = 0; k < 4; ++k) wrow[k] = *(const float4*)&wp[g0 + k][e0];
#pragma unroll
            for (int i = 0; i < 8; ++i) {
                const float4 xv = *(const float4*)&xs[bq8 + i][g0];
                const float xa[4] = {xv.x, xv.y, xv.z, xv.w};
#pragma unroll
                for (int k = 0; k < 4; ++k) {
                    acc[i][0] = fmaf(xa[k], wrow[k].x, acc[i][0]);
                    acc[i][1] = fmaf(xa[k], wrow[k].y, acc[i][1]);
                    acc[i][2] = fmaf(xa[k], wrow[k].z, acc[i][2]);
                    acc[i][3] = fmaf(xa[k], wrow[k].w, acc[i][3]);
                }
            }
        }
#pragma unroll
        for (int i = 0; i < 8; ++i)
#pragma unroll
            for (int j = 0; j < 4; ++j)
                macc[i][j] += fmaxf(acc[i][j] + bpr[j], 0.f);
        __syncthreads();
    }
#pragma unroll
    for (int i = 0; i < 8; ++i)
#pragma unroll
        for (int j = 0; j < 4; ++j)
            atomicAdd(&meanSum[(size_t)(b0 + bq8 + i) * kE + e0 + j], macc[i][j]);
}

// ---------------------------------------------------------------------------
// K2: query = relu([tissue_emb[t], mean] @ Wq + bq)  — grid kB, 128 threads
// ---------------------------------------------------------------------------
__global__ __launch_bounds__(128) void k_query(
    const int* __restrict__ x_tissue, const float* __restrict__ tissue_emb,
    const float* __restrict__ meanSum, const float* __restrict__ Wq,
    const float* __restrict__ bqv, float* __restrict__ query)
{
    __shared__ float comb[2 * kE];
    const int b = blockIdx.x, tid = threadIdx.x;
    const int t = x_tissue[b];
    comb[tid] = tissue_emb[t * kE + tid];
    comb[kE + tid] = meanSum[(size_t)b * kE + tid] * (1.0f / (float)kP);
    __syncthreads();
    float a = bqv[tid];
#pragma unroll 8
    for (int k = 0; k < 2 * kE; ++k) a = fmaf(comb[k], Wq[k * kE + tid], a);
    query[(size_t)b * kE + tid] = fmaxf(a, 0.f);
}

// ---------------------------------------------------------------------------
// K3: token GEMM pass B — recompute tokens; scores; online softmax; partial ctx
// grid (kNBT, kNPG), 256 threads
// ---------------------------------------------------------------------------
__global__ __launch_bounds__(256) void k_scorepass(
    const float* __restrict__ xg, const int* __restrict__ pidx,
    const float* __restrict__ Wp, const float* __restrict__ bp,
    const float* __restrict__ query,
    float* __restrict__ part_m, float* __restrict__ part_l,
    float* __restrict__ part_ctx)
{
    __shared__ __align__(16) float wp[kG][kE];
    __shared__ __align__(16) float xs[kBT][kG];
    __shared__ float bps[kE];

    const int tid = threadIdx.x;
    const int b0  = blockIdx.x * kBT;
    const int pg  = blockIdx.y;
    const int eq  = tid & 31;
    const int e0  = eq * 4;
    const int bq8 = (tid >> 5) * 8;

    // per-thread copy of query fragments for its 8 rows x 4 cols
    float qreg[8][4];
#pragma unroll
    for (int i = 0; i < 8; ++i) {
        const float4 qv = *(const float4*)&query[(size_t)(b0 + bq8 + i) * kE + e0];
        qreg[i][0] = qv.x; qreg[i][1] = qv.y; qreg[i][2] = qv.z; qreg[i][3] = qv.w;
    }

    float m[8], l[8], ctx[8][4];
#pragma unroll
    for (int i = 0; i < 8; ++i) {
        m[i] = -1e30f; l[i] = 0.f;
#pragma unroll
        for (int j = 0; j < 4; ++j) ctx[i][j] = 0.f;
    }

    const int gfix = tid & 63;
    const int bb   = tid >> 6;
    const float rsqE = 0.08838834764831845f; // 1/sqrt(128)

    for (int pp = 0; pp < kPPG; ++pp) {
        const int p = pg * kPPG + pp;
        const float4* wsrc = (const float4*)(Wp + (size_t)p * kG * kE);
        float4* wdst = (float4*)(&wp[0][0]);
#pragma unroll
        for (int it = 0; it < 8; ++it) wdst[it * 256 + tid] = wsrc[it * 256 + tid];
        if (tid < kE) bps[tid] = bp[p * kE + tid];
        {
            const int c = pidx[p * kG + gfix];
#pragma unroll
            for (int it = 0; it < 16; ++it) {
                const int bi = bb * 16 + it;
                xs[bi][gfix] = xg[(size_t)(b0 + bi) * kNG + c];
            }
        }
        __syncthreads();

        float bpr[4];
#pragma unroll
        for (int j = 0; j < 4; ++j) bpr[j] = bps[e0 + j];

        float acc[8][4];
#pragma unroll
        for (int i = 0; i < 8; ++i)
#pragma unroll
            for (int j = 0; j < 4; ++j) acc[i][j] = 0.f;

#pragma unroll 4
        for (int gq = 0; gq < 16; ++gq) {
            const int g0 = gq * 4;
            float4 wrow[4];
#pragma unroll
            for (int k = 0; k < 4; ++k) wrow[k] = *(const float4*)&wp[g0 + k][e0];
#pragma unroll
            for (int i = 0; i < 8; ++i) {
                const float4 xv = *(const float4*)&xs[bq8 + i][g0];
                const float xa[4] = {xv.x, xv.y, xv.z, xv.w};
#pragma unroll
                for (int k = 0; k < 4; ++k) {
                    acc[i][0] = fmaf(xa[k], wrow[k].x, acc[i][0]);
                    acc[i][1] = fmaf(xa[k], wrow[k].y, acc[i][1]);
                    acc[i][2] = fmaf(xa[k], wrow[k].z, acc[i][2]);
                    acc[i][3] = fmaf(xa[k], wrow[k].w, acc[i][3]);
                }
            }
        }
        // tokens, score, online-softmax update
#pragma unroll
        for (int i = 0; i < 8; ++i) {
#pragma unroll
            for (int j = 0; j < 4; ++j) acc[i][j] = fmaxf(acc[i][j] + bpr[j], 0.f);
            float ps = acc[i][0] * qreg[i][0] + acc[i][1] * qreg[i][1]
                     + acc[i][2] * qreg[i][2] + acc[i][3] * qreg[i][3];
            ps += __shfl_xor(ps, 1);
            ps += __shfl_xor(ps, 2);
            ps += __shfl_xor(ps, 4);
            ps += __shfl_xor(ps, 8);
            ps += __shfl_xor(ps, 16);
            const float s  = ps * rsqE;
            const float mn = fmaxf(m[i], s);
            const float sc = __expf(m[i] - mn);
            const float w  = __expf(s - mn);
            l[i] = l[i] * sc + w;
#pragma unroll
            for (int j = 0; j < 4; ++j) ctx[i][j] = ctx[i][j] * sc + w * acc[i][j];
            m[i] = mn;
        }
        __syncthreads();
    }

    if (eq == 0) {
#pragma unroll
        for (int i = 0; i < 8; ++i) {
            part_m[(size_t)(b0 + bq8 + i) * kNPG + pg] = m[i];
            part_l[(size_t)(b0 + bq8 + i) * kNPG + pg] = l[i];
        }
    }
#pragma unroll
    for (int i = 0; i < 8; ++i)
#pragma unroll
        for (int j = 0; j < 4; ++j)
            part_ctx[((size_t)(b0 + bq8 + i) * kNPG + pg) * kE + e0 + j] = ctx[i][j];
}

// ---------------------------------------------------------------------------
// K4: merge online-softmax partials -> context  — grid kB, 128 threads
// ---------------------------------------------------------------------------
__global__ __launch_bounds__(128) void k_merge(
    const float* __restrict__ part_m, const float* __restrict__ part_l,
    const float* __restrict__ part_ctx, float* __restrict__ context)
{
    const int b = blockIdx.x, e = threadIdx.x;
    float M = -1e30f;
#pragma unroll
    for (int g = 0; g < kNPG; ++g) M = fmaxf(M, part_m[(size_t)b * kNPG + g]);
    float L = 0.f, cx = 0.f;
#pragma unroll
    for (int g = 0; g < kNPG; ++g) {
        const float w = __expf(part_m[(size_t)b * kNPG + g] - M);
        L  += part_l[(size_t)b * kNPG + g] * w;
        cx += w * part_ctx[((size_t)b * kNPG + g) * kE + e];
    }
    context[(size_t)b * kE + e] = cx / L;
}

// ---------------------------------------------------------------------------
// K5: qkv = context @ Wqkv + bqkv  — grid kB, 128 threads
// ---------------------------------------------------------------------------
__global__ __launch_bounds__(128) void k_qkv(
    const float* __restrict__ context, const float* __restrict__ Wqkv,
    const float* __restrict__ bqkv, float* __restrict__ qkv)
{
    __shared__ float cs[kE];
    const int b = blockIdx.x, tid = threadIdx.x;
    cs[tid] = context[(size_t)b * kE + tid];
    __syncthreads();
#pragma unroll
    for (int part = 0; part < 3; ++part) {
        const int col = part * kE + tid;
        float a = bqkv[col];
#pragma unroll 8
        for (int k = 0; k < kE; ++k) a = fmaf(cs[k], Wqkv[k * 3 * kE + col], a);
        qkv[(size_t)b * 3 * kE + col] = a;
    }
}

// ---------------------------------------------------------------------------
// K6: deterministic tissue-group build — 1 block, 64 threads
// ---------------------------------------------------------------------------
__global__ __launch_bounds__(64) void k_groups(
    const int* __restrict__ x_tissue, int* __restrict__ gstart,
    int* __restrict__ glist)
{
    __shared__ int cnts[kT];
    __shared__ int starts[kT + 1];
    const int tid = threadIdx.x;
    if (tid < kT) {
        int c = 0;
        for (int b = 0; b < kB; ++b) c += (x_tissue[b] == tid) ? 1 : 0;
        cnts[tid] = c;
    }
    __syncthreads();
    if (tid == 0) {
        int a = 0;
        for (int t = 0; t < kT; ++t) { starts[t] = a; a += cnts[t]; }
        starts[kT] = a;
    }
    __syncthreads();
    if (tid <= kT) gstart[tid] = starts[tid];
    if (tid < kT) {
        int off = starts[tid];
        for (int b = 0; b < kB; ++b)
            if (x_tissue[b] == tid) glist[off++] = b;
    }
}

// ---------------------------------------------------------------------------
// K7: grouped attention + Wo + LN-mix + MLP + normalize — grid kB, 256 threads
// ---------------------------------------------------------------------------
__global__ __launch_bounds__(256) void k_final(
    const int* __restrict__ x_tissue, const int* __restrict__ gstart,
    const int* __restrict__ glist, const float* __restrict__ qkv,
    const float* __restrict__ context, const float* __restrict__ Wo,
    const float* __restrict__ bo, const float* __restrict__ ln_g,
    const float* __restrict__ ln_b, const float* __restrict__ W1,
    const float* __restrict__ b1, const float* __restrict__ W2,
    const float* __restrict__ b2, float* __restrict__ out)
{
    __shared__ float qb[kE], att[kE], ctxb[kE], cf[kE], h1s[32];
    __shared__ float rsum[4], rsq[4];
    const int b = blockIdx.x, tid = threadIdx.x;
    const int t = x_tissue[b];
    const int s0 = gstart[t], s1 = gstart[t + 1];
    const int cnt = s1 - s0;
    if (tid < kE) {
        qb[tid]   = qkv[(size_t)b * 3 * kE + tid];
        ctxb[tid] = context[(size_t)b * kE + tid];
    }
    __syncthreads();

    const int h = tid >> 6;
    const int lane = tid & 63;
    const int d = lane & 31;
    const float qd = qb[h * 32 + d];
    float m = -1e30f, l = 0.f, o = 0.f;
    for (int j = 0; j < cnt; ++j) {
        const int c = glist[s0 + j];
        float s = qd * qkv[(size_t)c * 3 * kE + kE + h * 32 + d];
        s += __shfl_xor(s, 1);
        s += __shfl_xor(s, 2);
        s += __shfl_xor(s, 4);
        s += __shfl_xor(s, 8);
        s += __shfl_xor(s, 16);
        s *= 0.17677669529663687f; // 1/sqrt(32)
        const float mn = fmaxf(m, s);
        const float sc = __expf(m - mn);
        const float w  = __expf(s - mn);
        const float vd = qkv[(size_t)c * 3 * kE + 2 * kE + h * 32 + d];
        l = l * sc + w;
        o = o * sc + w * vd;
        m = mn;
    }
    if (lane < 32) att[h * 32 + d] = o / l;
    __syncthreads();

    float x = 0.f;
    if (tid < kE) {
        float a = bo[tid];
#pragma unroll 8
        for (int k = 0; k < kE; ++k) a = fmaf(att[k], Wo[k * kE + tid], a);
        x = 0.3f * a + 0.7f * ctxb[tid];
    }
    float sum = (tid < kE) ? x : 0.f;
    float sq  = (tid < kE) ? x * x : 0.f;
#pragma unroll
    for (int off = 1; off <= 32; off <<= 1) {
        sum += __shfl_xor(sum, off);
        sq  += __shfl_xor(sq, off);
    }
    if (lane == 0) { rsum[h] = sum; rsq[h] = sq; }
    __syncthreads();
    const float mu  = (rsum[0] + rsum[1] + rsum[2] + rsum[3]) * (1.0f / kE);
    const float var = (rsq[0] + rsq[1] + rsq[2] + rsq[3]) * (1.0f / kE) - mu * mu;
    if (tid < kE) {
        const float y = (x - mu) * rsqrtf(var + 1e-5f) * ln_g[tid] + ln_b[tid];
        cf[tid] = (cnt > 1) ? y : ctxb[tid];
    }
    __syncthreads();
    if (tid < 32) {
        float a = b1[tid];
#pragma unroll 8
        for (int e = 0; e < kE; ++e) a = fmaf(cf[e], W1[e * 32 + tid], a);
        h1s[tid] = fmaxf(a, 0.f);
    }
    __syncthreads();
    if (tid == 0) {
        float l0 = b2[0], l1 = b2[1];
#pragma unroll
        for (int j = 0; j < 32; ++j) {
            l0 = fmaf(h1s[j], W2[2 * j + 0], l0);
            l1 = fmaf(h1s[j], W2[2 * j + 1], l1);
        }
        const float nrm = sqrtf(l0 * l0 + l1 * l1);
        const float inv = 1.f / fmaxf(nrm, 1e-12f);
        out[2 * b + 0] = l0 * inv;
        out[2 * b + 1] = l1 * inv;
    }
}

// ---------------------------------------------------------------------------
extern "C" void kernel_launch(void* const* d_in, const int* in_sizes, int n_in,
                              void* d_out, int out_size, void* d_ws, size_t ws_size,
                              hipStream_t stream) {
    const float* x_genes    = (const float*)d_in[0];
    const int*   x_tissue   = (const int*)d_in[1];
    const int*   pathway_idx= (const int*)d_in[2];
    const float* Wp         = (const float*)d_in[3];
    const float* bp         = (const float*)d_in[4];
    const float* tissue_emb = (const float*)d_in[5];
    const float* Wq         = (const float*)d_in[6];
    const float* bqv        = (const float*)d_in[7];
    const float* Wqkv       = (const float*)d_in[8];
    const float* bqkv       = (const float*)d_in[9];
    const float* Wo         = (const float*)d_in[10];
    const float* bo         = (const float*)d_in[11];
    const float* ln_g       = (const float*)d_in[12];
    const float* ln_b       = (const float*)d_in[13];
    const float* W1         = (const float*)d_in[14];
    const float* b1         = (const float*)d_in[15];
    const float* W2         = (const float*)d_in[16];
    const float* b2         = (const float*)d_in[17];
    float* out = (float*)d_out;

    float* ws = (float*)d_ws;
    float* meanSum  = ws;                        // 262144
    float* query    = ws + 262144;               // 262144
    float* part_m   = ws + 524288;               // 32768
    float* part_l   = ws + 557056;               // 32768
    float* part_ctx = ws + 589824;               // 4194304
    float* context  = ws + 4784128;              // 262144
    float* qkv      = ws + 5046272;              // 786432
    int*   gstart   = (int*)(ws + 5832704);      // 33
    int*   glist    = gstart + 64;               // 2048

    hipMemsetAsync(meanSum, 0, (size_t)kB * kE * sizeof(float), stream);

    dim3 gridTok(kNBT, kNPG);
    k_meanpass<<<gridTok, 256, 0, stream>>>(x_genes, pathway_idx, Wp, bp, meanSum);
    k_query<<<kB, 128, 0, stream>>>(x_tissue, tissue_emb, meanSum, Wq, bqv, query);
    k_scorepass<<<gridTok, 256, 0, stream>>>(x_genes, pathway_idx, Wp, bp, query,
                                             part_m, part_l, part_ctx);
    k_merge<<<kB, 128, 0, stream>>>(part_m, part_l, part_ctx, context);
    k_qkv<<<kB, 128, 0, stream>>>(context, Wqkv, bqkv, qkv);
    k_groups<<<1, 64, 0, stream>>>(x_tissue, gstart, glist);
    k_final<<<kB, 256, 0, stream>>>(x_tissue, gstart, glist, qkv, context,
                                    Wo, bo, ln_g, ln_b, W1, b1, W2, b2, out);
}

// Round 3
// 659.667 us; speedup vs baseline: 1.8319x; 1.8319x over previous
//
#include <hip/hip_runtime.h>
#include <math.h>

// Problem constants
constexpr int kB  = 2048;
constexpr int kNG = 20000;
constexpr int kP  = 256;
constexpr int kG  = 64;
constexpr int kE  = 128;
constexpr int kT  = 32;
constexpr int kNPG = 16;   // number of pathway groups
constexpr int kPPG = 16;   // pathways per group
constexpr int kBT  = 64;   // batch tile
constexpr int kNBT = kB / kBT; // 32

// ---------------------------------------------------------------------------
// T0: transpose x_genes [B][NG] f32 -> xgT [NG][B] f32 (exact)
// grid (ceil(NG/64)=313, B/64=32), 256 threads
// ---------------------------------------------------------------------------
__global__ __launch_bounds__(256) void k_transpose(
    const float* __restrict__ xg, float* __restrict__ xgT)
{
    __shared__ float t[64][65];
    const int g0 = blockIdx.x * 64, b0 = blockIdx.y * 64;
    const int lx = threadIdx.x & 63, ly = threadIdx.x >> 6;
#pragma unroll
    for (int i = 0; i < 16; ++i) {
        const int r = ly * 16 + i;
        const int g = g0 + lx;
        t[r][lx] = (g < kNG) ? xg[(size_t)(b0 + r) * kNG + g] : 0.f;
    }
    __syncthreads();
#pragma unroll
    for (int i = 0; i < 16; ++i) {
        const int gr = ly * 16 + i;
        const int g = g0 + gr;
        if (g < kNG) xgT[(size_t)g * kB + b0 + lx] = t[lx][gr];
    }
}

// ---------------------------------------------------------------------------
// Pass A: token GEMM (coalesced gather from xgT) -> meanSum accumulation
// grid (kNBT, kNPG), 256 threads
// ---------------------------------------------------------------------------
__global__ __launch_bounds__(256) void k_meanpass(
    const float* __restrict__ xgT, const int* __restrict__ pidx,
    const float* __restrict__ Wp, const float* __restrict__ bp,
    float* __restrict__ meanSum)
{
    __shared__ __align__(16) float wp[kG][kE];   // 32 KB
    __shared__ __align__(16) float xs[kBT][66];  // 16.5 KB
    __shared__ float bps[kE];

    const int tid = threadIdx.x;
    const int b0  = blockIdx.x * kBT;
    const int pg  = blockIdx.y;
    const int eq  = tid & 31;
    const int e0  = eq * 4;
    const int bq8 = (tid >> 5) * 8;
    const int lane = tid & 63;
    const int wv   = tid >> 6;

    float macc[8][4];
#pragma unroll
    for (int i = 0; i < 8; ++i)
#pragma unroll
        for (int j = 0; j < 4; ++j) macc[i][j] = 0.f;

    for (int pp = 0; pp < kPPG; ++pp) {
        const int p = pg * kPPG + pp;
        const float4* wsrc = (const float4*)(Wp + (size_t)p * kG * kE);
        float4* wdst = (float4*)(&wp[0][0]);
#pragma unroll
        for (int it = 0; it < 8; ++it) wdst[it * 256 + tid] = wsrc[it * 256 + tid];
        if (tid < kE) bps[tid] = bp[p * kE + tid];
        // coalesced gather: wave lane = batch index, wave covers gene pairs
#pragma unroll
        for (int gp = wv; gp < 32; gp += 4) {
            const int c0 = pidx[p * kG + 2 * gp];
            const int c1 = pidx[p * kG + 2 * gp + 1];
            const float v0 = xgT[(size_t)c0 * kB + b0 + lane];
            const float v1 = xgT[(size_t)c1 * kB + b0 + lane];
            *(float2*)&xs[lane][2 * gp] = make_float2(v0, v1);
        }
        __syncthreads();

        float bpr[4];
#pragma unroll
        for (int j = 0; j < 4; ++j) bpr[j] = bps[e0 + j];

        float acc[8][4];
#pragma unroll
        for (int i = 0; i < 8; ++i)
#pragma unroll
            for (int j = 0; j < 4; ++j) acc[i][j] = 0.f;

#pragma unroll 4
        for (int gq = 0; gq < 16; ++gq) {
            const int g0 = gq * 4;
            float4 wrow[4];
#pragma unroll
            for (int k = 0; k < 4; ++k) wrow[k] = *(const float4*)&wp[g0 + k][e0];
#pragma unroll
            for (int i = 0; i < 8; ++i) {
                const float2 xa01 = *(const float2*)&xs[bq8 + i][g0];
                const float2 xa23 = *(const float2*)&xs[bq8 + i][g0 + 2];
                const float xa[4] = {xa01.x, xa01.y, xa23.x, xa23.y};
#pragma unroll
                for (int k = 0; k < 4; ++k) {
                    acc[i][0] = fmaf(xa[k], wrow[k].x, acc[i][0]);
                    acc[i][1] = fmaf(xa[k], wrow[k].y, acc[i][1]);
                    acc[i][2] = fmaf(xa[k], wrow[k].z, acc[i][2]);
                    acc[i][3] = fmaf(xa[k], wrow[k].w, acc[i][3]);
                }
            }
        }
#pragma unroll
        for (int i = 0; i < 8; ++i)
#pragma unroll
            for (int j = 0; j < 4; ++j)
                macc[i][j] += fmaxf(acc[i][j] + bpr[j], 0.f);
        __syncthreads();
    }
#pragma unroll
    for (int i = 0; i < 8; ++i)
#pragma unroll
        for (int j = 0; j < 4; ++j)
            atomicAdd(&meanSum[(size_t)(b0 + bq8 + i) * kE + e0 + j], macc[i][j]);
}

// ---------------------------------------------------------------------------
// Pass B: token GEMM (coalesced gather) + scores + online softmax + ctx
// grid (kNBT, kNPG), 256 threads
// ---------------------------------------------------------------------------
__global__ __launch_bounds__(256) void k_scorepass(
    const float* __restrict__ xgT, const int* __restrict__ pidx,
    const float* __restrict__ Wp, const float* __restrict__ bp,
    const float* __restrict__ query,
    float* __restrict__ part_m, float* __restrict__ part_l,
    float* __restrict__ part_ctx)
{
    __shared__ __align__(16) float wp[kG][kE];
    __shared__ __align__(16) float xs[kBT][66];
    __shared__ float bps[kE];

    const int tid = threadIdx.x;
    const int b0  = blockIdx.x * kBT;
    const int pg  = blockIdx.y;
    const int eq  = tid & 31;
    const int e0  = eq * 4;
    const int bq8 = (tid >> 5) * 8;
    const int lane = tid & 63;
    const int wv   = tid >> 6;

    float qreg[8][4];
#pragma unroll
    for (int i = 0; i < 8; ++i) {
        const float4 qv = *(const float4*)&query[(size_t)(b0 + bq8 + i) * kE + e0];
        qreg[i][0] = qv.x; qreg[i][1] = qv.y; qreg[i][2] = qv.z; qreg[i][3] = qv.w;
    }

    float m[8], l[8], ctx[8][4];
#pragma unroll
    for (int i = 0; i < 8; ++i) {
        m[i] = -1e30f; l[i] = 0.f;
#pragma unroll
        for (int j = 0; j < 4; ++j) ctx[i][j] = 0.f;
    }

    const float rsqE = 0.08838834764831845f; // 1/sqrt(128)

    for (int pp = 0; pp < kPPG; ++pp) {
        const int p = pg * kPPG + pp;
        const float4* wsrc = (const float4*)(Wp + (size_t)p * kG * kE);
        float4* wdst = (float4*)(&wp[0][0]);
#pragma unroll
        for (int it = 0; it < 8; ++it) wdst[it * 256 + tid] = wsrc[it * 256 + tid];
        if (tid < kE) bps[tid] = bp[p * kE + tid];
#pragma unroll
        for (int gp = wv; gp < 32; gp += 4) {
            const int c0 = pidx[p * kG + 2 * gp];
            const int c1 = pidx[p * kG + 2 * gp + 1];
            const float v0 = xgT[(size_t)c0 * kB + b0 + lane];
            const float v1 = xgT[(size_t)c1 * kB + b0 + lane];
            *(float2*)&xs[lane][2 * gp] = make_float2(v0, v1);
        }
        __syncthreads();

        float bpr[4];
#pragma unroll
        for (int j = 0; j < 4; ++j) bpr[j] = bps[e0 + j];

        float acc[8][4];
#pragma unroll
        for (int i = 0; i < 8; ++i)
#pragma unroll
            for (int j = 0; j < 4; ++j) acc[i][j] = 0.f;

#pragma unroll 4
        for (int gq = 0; gq < 16; ++gq) {
            const int g0 = gq * 4;
            float4 wrow[4];
#pragma unroll
            for (int k = 0; k < 4; ++k) wrow[k] = *(const float4*)&wp[g0 + k][e0];
#pragma unroll
            for (int i = 0; i < 8; ++i) {
                const float2 xa01 = *(const float2*)&xs[bq8 + i][g0];
                const float2 xa23 = *(const float2*)&xs[bq8 + i][g0 + 2];
                const float xa[4] = {xa01.x, xa01.y, xa23.x, xa23.y};
#pragma unroll
                for (int k = 0; k < 4; ++k) {
                    acc[i][0] = fmaf(xa[k], wrow[k].x, acc[i][0]);
                    acc[i][1] = fmaf(xa[k], wrow[k].y, acc[i][1]);
                    acc[i][2] = fmaf(xa[k], wrow[k].z, acc[i][2]);
                    acc[i][3] = fmaf(xa[k], wrow[k].w, acc[i][3]);
                }
            }
        }
        // tokens, score, online-softmax update
#pragma unroll
        for (int i = 0; i < 8; ++i) {
#pragma unroll
            for (int j = 0; j < 4; ++j) acc[i][j] = fmaxf(acc[i][j] + bpr[j], 0.f);
            float ps = acc[i][0] * qreg[i][0] + acc[i][1] * qreg[i][1]
                     + acc[i][2] * qreg[i][2] + acc[i][3] * qreg[i][3];
            ps += __shfl_xor(ps, 1);
            ps += __shfl_xor(ps, 2);
            ps += __shfl_xor(ps, 4);
            ps += __shfl_xor(ps, 8);
            ps += __shfl_xor(ps, 16);
            const float s  = ps * rsqE;
            const float mn = fmaxf(m[i], s);
            const float sc = __expf(m[i] - mn);
            const float w  = __expf(s - mn);
            l[i] = l[i] * sc + w;
#pragma unroll
            for (int j = 0; j < 4; ++j) ctx[i][j] = ctx[i][j] * sc + w * acc[i][j];
            m[i] = mn;
        }
        __syncthreads();
    }

    if (eq == 0) {
#pragma unroll
        for (int i = 0; i < 8; ++i) {
            part_m[(size_t)(b0 + bq8 + i) * kNPG + pg] = m[i];
            part_l[(size_t)(b0 + bq8 + i) * kNPG + pg] = l[i];
        }
    }
#pragma unroll
    for (int i = 0; i < 8; ++i)
#pragma unroll
        for (int j = 0; j < 4; ++j)
            part_ctx[((size_t)(b0 + bq8 + i) * kNPG + pg) * kE + e0 + j] = ctx[i][j];
}

// ---------------------------------------------------------------------------
// Slow-path fallback kernels (R1-proven, uncoalesced gather) — ws too small
// ---------------------------------------------------------------------------
__global__ __launch_bounds__(256) void k_meanpass_slow(
    const float* __restrict__ xg, const int* __restrict__ pidx,
    const float* __restrict__ Wp, const float* __restrict__ bp,
    float* __restrict__ meanSum)
{
    __shared__ __align__(16) float wp[kG][kE];
    __shared__ __align__(16) float xs[kBT][kG];
    __shared__ float bps[kE];

    const int tid = threadIdx.x;
    const int b0  = blockIdx.x * kBT;
    const int pg  = blockIdx.y;
    const int eq  = tid & 31;
    const int e0  = eq * 4;
    const int bq8 = (tid >> 5) * 8;

    float macc[8][4];
#pragma unroll
    for (int i = 0; i < 8; ++i)
#pragma unroll
        for (int j = 0; j < 4; ++j) macc[i][j] = 0.f;

    const int gfix = tid & 63;
    const int bb   = tid >> 6;

    for (int pp = 0; pp < kPPG; ++pp) {
        const int p = pg * kPPG + pp;
        const float4* wsrc = (const float4*)(Wp + (size_t)p * kG * kE);
        float4* wdst = (float4*)(&wp[0][0]);
#pragma unroll
        for (int it = 0; it < 8; ++it) wdst[it * 256 + tid] = wsrc[it * 256 + tid];
        if (tid < kE) bps[tid] = bp[p * kE + tid];
        {
            const int c = pidx[p * kG + gfix];
#pragma unroll
            for (int it = 0; it < 16; ++it) {
                const int bi = bb * 16 + it;
                xs[bi][gfix] = xg[(size_t)(b0 + bi) * kNG + c];
            }
        }
        __syncthreads();

        float bpr[4];
#pragma unroll
        for (int j = 0; j < 4; ++j) bpr[j] = bps[e0 + j];

        float acc[8][4];
#pragma unroll
        for (int i = 0; i < 8; ++i)
#pragma unroll
            for (int j = 0; j < 4; ++j) acc[i][j] = 0.f;

#pragma unroll 4
        for (int gq = 0; gq < 16; ++gq) {
            const int g0 = gq * 4;
            float4 wrow[4];
#pragma unroll
            for (int k = 0; k < 4; ++k) wrow[k] = *(const float4*)&wp[g0 + k][e0];
#pragma unroll
            for (int i = 0; i < 8; ++i) {
                const float4 xv = *(const float4*)&xs[bq8 + i][g0];
                const float xa[4] = {xv.x, xv.y, xv.z, xv.w};
#pragma unroll
                for (int k = 0; k < 4; ++k) {
                    acc[i][0] = fmaf(xa[k], wrow[k].x, acc[i][0]);
                    acc[i][1] = fmaf(xa[k], wrow[k].y, acc[i][1]);
                    acc[i][2] = fmaf(xa[k], wrow[k].z, acc[i][2]);
                    acc[i][3] = fmaf(xa[k], wrow[k].w, acc[i][3]);
                }
            }
        }
#pragma unroll
        for (int i = 0; i < 8; ++i)
#pragma unroll
            for (int j = 0; j < 4; ++j)
                macc[i][j] += fmaxf(acc[i][j] + bpr[j], 0.f);
        __syncthreads();
    }
#pragma unroll
    for (int i = 0; i < 8; ++i)
#pragma unroll
        for (int j = 0; j < 4; ++j)
            atomicAdd(&meanSum[(size_t)(b0 + bq8 + i) * kE + e0 + j], macc[i][j]);
}

__global__ __launch_bounds__(256) void k_scorepass_slow(
    const float* __restrict__ xg, const int* __restrict__ pidx,
    const float* __restrict__ Wp, const float* __restrict__ bp,
    const float* __restrict__ query,
    float* __restrict__ part_m, float* __restrict__ part_l,
    float* __restrict__ part_ctx)
{
    __shared__ __align__(16) float wp[kG][kE];
    __shared__ __align__(16) float xs[kBT][kG];
    __shared__ float bps[kE];

    const int tid = threadIdx.x;
    const int b0  = blockIdx.x * kBT;
    const int pg  = blockIdx.y;
    const int eq  = tid & 31;
    const int e0  = eq * 4;
    const int bq8 = (tid >> 5) * 8;

    float qreg[8][4];
#pragma unroll
    for (int i = 0; i < 8; ++i) {
        const float4 qv = *(const float4*)&query[(size_t)(b0 + bq8 + i) * kE + e0];
        qreg[i][0] = qv.x; qreg[i][1] = qv.y; qreg[i][2] = qv.z; qreg[i][3] = qv.w;
    }

    float m[8], l[8], ctx[8][4];
#pragma unroll
    for (int i = 0; i < 8; ++i) {
        m[i] = -1e30f; l[i] = 0.f;
#pragma unroll
        for (int j = 0; j < 4; ++j) ctx[i][j] = 0.f;
    }

    const int gfix = tid & 63;
    const int bb   = tid >> 6;
    const float rsqE = 0.08838834764831845f;

    for (int pp = 0; pp < kPPG; ++pp) {
        const int p = pg * kPPG + pp;
        const float4* wsrc = (const float4*)(Wp + (size_t)p * kG * kE);
        float4* wdst = (float4*)(&wp[0][0]);
#pragma unroll
        for (int it = 0; it < 8; ++it) wdst[it * 256 + tid] = wsrc[it * 256 + tid];
        if (tid < kE) bps[tid] = bp[p * kE + tid];
        {
            const int c = pidx[p * kG + gfix];
#pragma unroll
            for (int it = 0; it < 16; ++it) {
                const int bi = bb * 16 + it;
                xs[bi][gfix] = xg[(size_t)(b0 + bi) * kNG + c];
            }
        }
        __syncthreads();

        float bpr[4];
#pragma unroll
        for (int j = 0; j < 4; ++j) bpr[j] = bps[e0 + j];

        float acc[8][4];
#pragma unroll
        for (int i = 0; i < 8; ++i)
#pragma unroll
            for (int j = 0; j < 4; ++j) acc[i][j] = 0.f;

#pragma unroll 4
        for (int gq = 0; gq < 16; ++gq) {
            const int g0 = gq * 4;
            float4 wrow[4];
#pragma unroll
            for (int k = 0; k < 4; ++k) wrow[k] = *(const float4*)&wp[g0 + k][e0];
#pragma unroll
            for (int i = 0; i < 8; ++i) {
                const float4 xv = *(const float4*)&xs[bq8 + i][g0];
                const float xa[4] = {xv.x, xv.y, xv.z, xv.w};
#pragma unroll
                for (int k = 0; k < 4; ++k) {
                    acc[i][0] = fmaf(xa[k], wrow[k].x, acc[i][0]);
                    acc[i][1] = fmaf(xa[k], wrow[k].y, acc[i][1]);
                    acc[i][2] = fmaf(xa[k], wrow[k].z, acc[i][2]);
                    acc[i][3] = fmaf(xa[k], wrow[k].w, acc[i][3]);
                }
            }
        }
#pragma unroll
        for (int i = 0; i < 8; ++i) {
#pragma unroll
            for (int j = 0; j < 4; ++j) acc[i][j] = fmaxf(acc[i][j] + bpr[j], 0.f);
            float ps = acc[i][0] * qreg[i][0] + acc[i][1] * qreg[i][1]
                     + acc[i][2] * qreg[i][2] + acc[i][3] * qreg[i][3];
            ps += __shfl_xor(ps, 1);
            ps += __shfl_xor(ps, 2);
            ps += __shfl_xor(ps, 4);
            ps += __shfl_xor(ps, 8);
            ps += __shfl_xor(ps, 16);
            const float s  = ps * rsqE;
            const float mn = fmaxf(m[i], s);
            const float sc = __expf(m[i] - mn);
            const float w  = __expf(s - mn);
            l[i] = l[i] * sc + w;
#pragma unroll
            for (int j = 0; j < 4; ++j) ctx[i][j] = ctx[i][j] * sc + w * acc[i][j];
            m[i] = mn;
        }
        __syncthreads();
    }

    if (eq == 0) {
#pragma unroll
        for (int i = 0; i < 8; ++i) {
            part_m[(size_t)(b0 + bq8 + i) * kNPG + pg] = m[i];
            part_l[(size_t)(b0 + bq8 + i) * kNPG + pg] = l[i];
        }
    }
#pragma unroll
    for (int i = 0; i < 8; ++i)
#pragma unroll
        for (int j = 0; j < 4; ++j)
            part_ctx[((size_t)(b0 + bq8 + i) * kNPG + pg) * kE + e0 + j] = ctx[i][j];
}

// ---------------------------------------------------------------------------
// Shared small kernels
// ---------------------------------------------------------------------------
__global__ __launch_bounds__(128) void k_query(
    const int* __restrict__ x_tissue, const float* __restrict__ tissue_emb,
    const float* __restrict__ meanSum, const float* __restrict__ Wq,
    const float* __restrict__ bqv, float* __restrict__ query)
{
    __shared__ float comb[2 * kE];
    const int b = blockIdx.x, tid = threadIdx.x;
    const int t = x_tissue[b];
    comb[tid] = tissue_emb[t * kE + tid];
    comb[kE + tid] = meanSum[(size_t)b * kE + tid] * (1.0f / (float)kP);
    __syncthreads();
    float a = bqv[tid];
#pragma unroll 8
    for (int k = 0; k < 2 * kE; ++k) a = fmaf(comb[k], Wq[k * kE + tid], a);
    query[(size_t)b * kE + tid] = fmaxf(a, 0.f);
}

__global__ __launch_bounds__(128) void k_merge(
    const float* __restrict__ part_m, const float* __restrict__ part_l,
    const float* __restrict__ part_ctx, float* __restrict__ context)
{
    const int b = blockIdx.x, e = threadIdx.x;
    float M = -1e30f;
#pragma unroll
    for (int g = 0; g < kNPG; ++g) M = fmaxf(M, part_m[(size_t)b * kNPG + g]);
    float L = 0.f, cx = 0.f;
#pragma unroll
    for (int g = 0; g < kNPG; ++g) {
        const float w = __expf(part_m[(size_t)b * kNPG + g] - M);
        L  += part_l[(size_t)b * kNPG + g] * w;
        cx += w * part_ctx[((size_t)b * kNPG + g) * kE + e];
    }
    context[(size_t)b * kE + e] = cx / L;
}

__global__ __launch_bounds__(128) void k_qkv(
    const float* __restrict__ context, const float* __restrict__ Wqkv,
    const float* __restrict__ bqkv, float* __restrict__ qkv)
{
    __shared__ float cs[kE];
    const int b = blockIdx.x, tid = threadIdx.x;
    cs[tid] = context[(size_t)b * kE + tid];
    __syncthreads();
#pragma unroll
    for (int part = 0; part < 3; ++part) {
        const int col = part * kE + tid;
        float a = bqkv[col];
#pragma unroll 8
        for (int k = 0; k < kE; ++k) a = fmaf(cs[k], Wqkv[k * 3 * kE + col], a);
        qkv[(size_t)b * 3 * kE + col] = a;
    }
}

__global__ __launch_bounds__(64) void k_groups(
    const int* __restrict__ x_tissue, int* __restrict__ gstart,
    int* __restrict__ glist)
{
    __shared__ int cnts[kT];
    __shared__ int starts[kT + 1];
    const int tid = threadIdx.x;
    if (tid < kT) {
        int c = 0;
        for (int b = 0; b < kB; ++b) c += (x_tissue[b] == tid) ? 1 : 0;
        cnts[tid] = c;
    }
    __syncthreads();
    if (tid == 0) {
        int a = 0;
        for (int t = 0; t < kT; ++t) { starts[t] = a; a += cnts[t]; }
        starts[kT] = a;
    }
    __syncthreads();
    if (tid <= kT) gstart[tid] = starts[tid];
    if (tid < kT) {
        int off = starts[tid];
        for (int b = 0; b < kB; ++b)
            if (x_tissue[b] == tid) glist[off++] = b;
    }
}

__global__ __launch_bounds__(256) void k_final(
    const int* __restrict__ x_tissue, const int* __restrict__ gstart,
    const int* __restrict__ glist, const float* __restrict__ qkv,
    const float* __restrict__ context, const float* __restrict__ Wo,
    const float* __restrict__ bo, const float* __restrict__ ln_g,
    const float* __restrict__ ln_b, const float* __restrict__ W1,
    const float* __restrict__ b1, const float* __restrict__ W2,
    const float* __restrict__ b2, float* __restrict__ out)
{
    __shared__ float qb[kE], att[kE], ctxb[kE], cf[kE], h1s[32];
    __shared__ float rsum[4], rsq[4];
    const int b = blockIdx.x, tid = threadIdx.x;
    const int t = x_tissue[b];
    const int s0 = gstart[t], s1 = gstart[t + 1];
    const int cnt = s1 - s0;
    if (tid < kE) {
        qb[tid]   = qkv[(size_t)b * 3 * kE + tid];
        ctxb[tid] = context[(size_t)b * kE + tid];
    }
    __syncthreads();

    const int h = tid >> 6;
    const int lane = tid & 63;
    const int d = lane & 31;
    const float qd = qb[h * 32 + d];
    float m = -1e30f, l = 0.f, o = 0.f;
    for (int j = 0; j < cnt; ++j) {
        const int c = glist[s0 + j];
        float s = qd * qkv[(size_t)c * 3 * kE + kE + h * 32 + d];
        s += __shfl_xor(s, 1);
        s += __shfl_xor(s, 2);
        s += __shfl_xor(s, 4);
        s += __shfl_xor(s, 8);
        s += __shfl_xor(s, 16);
        s *= 0.17677669529663687f; // 1/sqrt(32)
        const float mn = fmaxf(m, s);
        const float sc = __expf(m - mn);
        const float w  = __expf(s - mn);
        const float vd = qkv[(size_t)c * 3 * kE + 2 * kE + h * 32 + d];
        l = l * sc + w;
        o = o * sc + w * vd;
        m = mn;
    }
    if (lane < 32) att[h * 32 + d] = o / l;
    __syncthreads();

    float x = 0.f;
    if (tid < kE) {
        float a = bo[tid];
#pragma unroll 8
        for (int k = 0; k < kE; ++k) a = fmaf(att[k], Wo[k * kE + tid], a);
        x = 0.3f * a + 0.7f * ctxb[tid];
    }
    float sum = (tid < kE) ? x : 0.f;
    float sq  = (tid < kE) ? x * x : 0.f;
#pragma unroll
    for (int off = 1; off <= 32; off <<= 1) {
        sum += __shfl_xor(sum, off);
        sq  += __shfl_xor(sq, off);
    }
    if (lane == 0) { rsum[h] = sum; rsq[h] = sq; }
    __syncthreads();
    const float mu  = (rsum[0] + rsum[1] + rsum[2] + rsum[3]) * (1.0f / kE);
    const float var = (rsq[0] + rsq[1] + rsq[2] + rsq[3]) * (1.0f / kE) - mu * mu;
    if (tid < kE) {
        const float y = (x - mu) * rsqrtf(var + 1e-5f) * ln_g[tid] + ln_b[tid];
        cf[tid] = (cnt > 1) ? y : ctxb[tid];
    }
    __syncthreads();
    if (tid < 32) {
        float a = b1[tid];
#pragma unroll 8
        for (int e = 0; e < kE; ++e) a = fmaf(cf[e], W1[e * 32 + tid], a);
        h1s[tid] = fmaxf(a, 0.f);
    }
    __syncthreads();
    if (tid == 0) {
        float l0 = b2[0], l1 = b2[1];
#pragma unroll
        for (int j = 0; j < 32; ++j) {
            l0 = fmaf(h1s[j], W2[2 * j + 0], l0);
            l1 = fmaf(h1s[j], W2[2 * j + 1], l1);
        }
        const float nrm = sqrtf(l0 * l0 + l1 * l1);
        const float inv = 1.f / fmaxf(nrm, 1e-12f);
        out[2 * b + 0] = l0 * inv;
        out[2 * b + 1] = l1 * inv;
    }
}

// ---------------------------------------------------------------------------
extern "C" void kernel_launch(void* const* d_in, const int* in_sizes, int n_in,
                              void* d_out, int out_size, void* d_ws, size_t ws_size,
                              hipStream_t stream) {
    const float* x_genes    = (const float*)d_in[0];
    const int*   x_tissue   = (const int*)d_in[1];
    const int*   pathway_idx= (const int*)d_in[2];
    const float* Wp         = (const float*)d_in[3];
    const float* bp         = (const float*)d_in[4];
    const float* tissue_emb = (const float*)d_in[5];
    const float* Wq         = (const float*)d_in[6];
    const float* bqv        = (const float*)d_in[7];
    const float* Wqkv       = (const float*)d_in[8];
    const float* bqkv       = (const float*)d_in[9];
    const float* Wo         = (const float*)d_in[10];
    const float* bo         = (const float*)d_in[11];
    const float* ln_g       = (const float*)d_in[12];
    const float* ln_b       = (const float*)d_in[13];
    const float* W1         = (const float*)d_in[14];
    const float* b1         = (const float*)d_in[15];
    const float* W2         = (const float*)d_in[16];
    const float* b2         = (const float*)d_in[17];
    float* out = (float*)d_out;

    char* w = (char*)d_ws;
    size_t off = 0;
    auto carve = [&](size_t bytes) -> void* {
        void* p = (void*)(w + off);
        off += (bytes + 255) & ~(size_t)255;
        return p;
    };
    float* meanSum  = (float*)carve((size_t)kB * kE * 4);
    float* query    = (float*)carve((size_t)kB * kE * 4);
    float* part_m   = (float*)carve((size_t)kB * kNPG * 4);
    float* part_l   = (float*)carve((size_t)kB * kNPG * 4);
    float* part_ctx = (float*)carve((size_t)kB * kNPG * kE * 4);
    float* context  = (float*)carve((size_t)kB * kE * 4);
    float* qkv      = (float*)carve((size_t)kB * 3 * kE * 4);
    int*   gstart   = (int*)carve(256);
    int*   glist    = (int*)carve((size_t)kB * 4);
    float* xgT      = (float*)carve((size_t)kNG * kB * 4);  // 164 MB, f32
    const bool fast = (off <= ws_size);

    hipMemsetAsync(meanSum, 0, (size_t)kB * kE * sizeof(float), stream);

    dim3 gridTok(kNBT, kNPG);
    if (fast) {
        dim3 gridTr((kNG + 63) / 64, kB / 64);
        k_transpose<<<gridTr, 256, 0, stream>>>(x_genes, xgT);
        k_meanpass<<<gridTok, 256, 0, stream>>>(xgT, pathway_idx, Wp, bp, meanSum);
        k_query<<<kB, 128, 0, stream>>>(x_tissue, tissue_emb, meanSum, Wq, bqv, query);
        k_scorepass<<<gridTok, 256, 0, stream>>>(xgT, pathway_idx, Wp, bp, query,
                                                 part_m, part_l, part_ctx);
    } else {
        k_meanpass_slow<<<gridTok, 256, 0, stream>>>(x_genes, pathway_idx, Wp, bp, meanSum);
        k_query<<<kB, 128, 0, stream>>>(x_tissue, tissue_emb, meanSum, Wq, bqv, query);
        k_scorepass_slow<<<gridTok, 256, 0, stream>>>(x_genes, pathway_idx, Wp, bp, query,
                                                      part_m, part_l, part_ctx);
    }
    k_merge<<<kB, 128, 0, stream>>>(part_m, part_l, part_ctx, context);
    k_qkv<<<kB, 128, 0, stream>>>(context, Wqkv, bqkv, qkv);
    k_groups<<<1, 64, 0, stream>>>(x_tissue, gstart, glist);
    k_final<<<kB, 256, 0, stream>>>(x_tissue, gstart, glist, qkv, context,
                                    Wo, bo, ln_g, ln_b, W1, b1, W2, b2, out);
}